// Round 1
// baseline (1045.752 us; speedup 1.0000x reference)
//
#include <hip/hip_runtime.h>

#define HIDDEN 5120
#define NEXP 160
#define NGRP 8
#define GSIZE 20
#define TOPKG 3
#define TOPK 6

#define TM 64     // tokens per block
#define KC 40     // k-chunk
#define EPW 16    // experts per wave
#define NW 10     // waves per block (10*16 = 160 experts)

// ---------- K0: transpose W [160][5120] -> wT [5120][160] ----------
__global__ __launch_bounds__(256) void transpose_w(const float* __restrict__ w,
                                                   float* __restrict__ wT) {
    int idx = blockIdx.x * 256 + threadIdx.x;
    if (idx >= HIDDEN * NEXP) return;
    int e = idx % NEXP;
    int k = idx / NEXP;
    wT[idx] = w[(size_t)e * HIDDEN + k];
}

// ---------- K1: logits[t][e] = sum_k x[t][k] * w[e][k] ----------
// block: 640 threads = 10 waves. lane = token (64 tokens), wave = 16 experts.
// W read via wave-uniform scalar loads from transposed wT.
__global__ __launch_bounds__(640, 1) void gemm_logits(const float* __restrict__ x,
                                                      const float* __restrict__ wT,
                                                      float* __restrict__ logits) {
    __shared__ float xs[TM][KC + 1];   // stride 41 words -> conflict-free-ish

    const int tid  = threadIdx.x;
    const int lane = tid & 63;
    const int wv   = tid >> 6;                       // 0..9
    const int t0   = blockIdx.x * TM;
    const int e0   = __builtin_amdgcn_readfirstlane(wv * EPW);  // force SGPR

    // staging assignment: each thread loads one float4 of the 64x40 tile
    const int i  = tid / (KC / 4);                   // token row 0..63
    const int jb = tid % (KC / 4);                   // 0..9
    const float* xrow = x + (size_t)(t0 + i) * HIDDEN + jb * 4;

    float acc[EPW];
#pragma unroll
    for (int j = 0; j < EPW; ++j) acc[j] = 0.f;

    const int NCH = HIDDEN / KC;                     // 128 chunks
    float4 v = *(const float4*)(xrow);               // prefetch chunk 0

    for (int c = 0; c < NCH; ++c) {
        __syncthreads();                             // prev compute done
        xs[i][jb * 4 + 0] = v.x;
        xs[i][jb * 4 + 1] = v.y;
        xs[i][jb * 4 + 2] = v.z;
        xs[i][jb * 4 + 3] = v.w;
        __syncthreads();

        int cn = (c + 1 < NCH) ? c + 1 : c;          // prefetch next chunk
        v = *(const float4*)(xrow + (size_t)cn * KC);

        const float* wp = wT + (size_t)c * KC * NEXP + e0;

        // chunk-local accumulator (2-level sum: ~6x lower rounding error)
        float cacc[EPW];
#pragma unroll
        for (int j = 0; j < EPW; ++j) cacc[j] = 0.f;

#pragma unroll
        for (int kk = 0; kk < KC; ++kk) {
            float xv = xs[lane][kk];
            const float* wr = wp + kk * NEXP;        // wave-uniform -> s_load
#pragma unroll
            for (int j = 0; j < EPW; ++j)
                cacc[j] = fmaf(xv, wr[j], cacc[j]);
        }
#pragma unroll
        for (int j = 0; j < EPW; ++j) acc[j] += cacc[j];
    }

    float* lp = logits + (size_t)(t0 + lane) * NEXP + e0;
#pragma unroll
    for (int j = 0; j < EPW; j += 4)
        *(float4*)(lp + j) = make_float4(acc[j], acc[j + 1], acc[j + 2], acc[j + 3]);
}

// ---------- K2: per-token grouped top-k epilogue ----------
// one thread per token; softmax denominator cancels, only exp(l - max) needed.
__global__ __launch_bounds__(64) void moe_topk(const float* __restrict__ logits,
                                               float* __restrict__ out, int T) {
    int t = blockIdx.x * 64 + threadIdx.x;
    if (t >= T) return;
    const float* row = logits + (size_t)t * NEXP;

    // group maxes (monotone: logits, not softmax)
    float gmax[NGRP];
#pragma unroll
    for (int g = 0; g < NGRP; ++g) {
        const float4* rp = (const float4*)(row + g * GSIZE);
        float4 a = rp[0], b = rp[1], c = rp[2], d = rp[3], e = rp[4];
        float m = a.x;
        m = fmaxf(m, a.y); m = fmaxf(m, a.z); m = fmaxf(m, a.w);
        m = fmaxf(m, b.x); m = fmaxf(m, b.y); m = fmaxf(m, b.z); m = fmaxf(m, b.w);
        m = fmaxf(m, c.x); m = fmaxf(m, c.y); m = fmaxf(m, c.z); m = fmaxf(m, c.w);
        m = fmaxf(m, d.x); m = fmaxf(m, d.y); m = fmaxf(m, d.z); m = fmaxf(m, d.w);
        m = fmaxf(m, e.x); m = fmaxf(m, e.y); m = fmaxf(m, e.z); m = fmaxf(m, e.w);
        gmax[g] = m;
    }

    // top-3 groups: repeated argmax, strict > => lowest index wins ties (matches lax.top_k)
    unsigned gm = 0;
#pragma unroll
    for (int r = 0; r < TOPKG; ++r) {
        float bv = -1e30f; int bi = 0;
#pragma unroll
        for (int g = 0; g < NGRP; ++g) {
            bool elig = !((gm >> g) & 1);
            if (elig && gmax[g] > bv) { bv = gmax[g]; bi = g; }
        }
        gm |= 1u << bi;
    }

    // top-6 experts within selected groups.
    // lexicographic threshold (pv,pi) excludes already-picked without a full mask.
    float pv = 1e30f; int pi = -1;
    float vals[TOPK]; int idxs[TOPK];
#pragma unroll
    for (int r = 0; r < TOPK; ++r) {
        float bv = -1e30f; int bi = 0;
        for (int g = 0; g < NGRP; ++g) {
            if (!((gm >> g) & 1)) continue;
#pragma unroll
            for (int j = 0; j < GSIZE; ++j) {
                int e = g * GSIZE + j;
                float vv = row[e];
                bool elig = (vv < pv) || (vv == pv && e > pi);
                if (elig && vv > bv) { bv = vv; bi = e; }
            }
        }
        vals[r] = bv; idxs[r] = bi; pv = bv; pi = bi;
    }

    // weights: exp(l - m) / sum  (global softmax denom cancels; m = vals[0] is the
    // global max since the top group always survives group selection)
    float m = vals[0];
    float s = 0.f, wv[TOPK];
#pragma unroll
    for (int r = 0; r < TOPK; ++r) { wv[r] = expf(vals[r] - m); s += wv[r]; }
    float inv = 1.f / (s + 1e-20f);

#pragma unroll
    for (int r = 0; r < TOPK; ++r) {
        out[(size_t)t * TOPK + r] = (float)idxs[r];                    // topk_idx
        out[(size_t)T * TOPK + (size_t)t * TOPK + r] = wv[r] * inv;    // topk_weight
    }
}

extern "C" void kernel_launch(void* const* d_in, const int* in_sizes, int n_in,
                              void* d_out, int out_size, void* d_ws, size_t ws_size,
                              hipStream_t stream) {
    const float* x = (const float*)d_in[0];
    const float* w = (const float*)d_in[1];
    float* out = (float*)d_out;
    const int T = in_sizes[0] / HIDDEN;              // 16384

    float* wT     = (float*)d_ws;                    // 5120*160 floats
    float* logits = wT + (size_t)HIDDEN * NEXP;      // T*160 floats

    transpose_w<<<(HIDDEN * NEXP + 255) / 256, 256, 0, stream>>>(w, wT);
    gemm_logits<<<T / TM, 640, 0, stream>>>(x, wT, logits);
    moe_topk<<<(T + 63) / 64, 64, 0, stream>>>(logits, out, T);
}

// Round 2
// 735.061 us; speedup vs baseline: 1.4227x; 1.4227x over previous
//
#include <hip/hip_runtime.h>

#define HIDDEN 5120
#define NEXP 160
#define NGRP 8
#define GSIZE 20
#define TOPKG 3
#define TOPK 6

// ---- K1 (GEMM) params ----
#define TM 64                    // tokens per block (= lanes per wave)
#define KC 32                    // k-chunk staged in LDS
#define EPW 20                   // experts per wave; 4 waves -> 80 experts = half
#define KSPLIT 2                 // K-split factor (adds waves; partials summed in K2)
#define KHALF (HIDDEN / KSPLIT)  // 2560
#define NCH (KHALF / KC)         // 80 chunks per block

// ---------- K0: transpose W [160][5120] -> wT [5120][160] ----------
__global__ __launch_bounds__(256) void transpose_w(const float* __restrict__ w,
                                                   float* __restrict__ wT) {
    int idx = blockIdx.x * 256 + threadIdx.x;
    if (idx >= HIDDEN * NEXP) return;
    int e = idx % NEXP;
    int k = idx / NEXP;
    wT[idx] = w[(size_t)e * HIDDEN + k];
}

// ---------- K1: partial logits via scalar-broadcast FMA ----------
// lane = token (64/wave); w rows wave-uniform -> s_load into SGPRs, FMA v,s,v.
// grid = (T/64) tiles x 2 expert-halves x KSPLIT  = 1024 blocks -> 16 waves/CU.
__global__ __launch_bounds__(256, 4) void gemm_logits(const float* __restrict__ x,
                                                      const float* __restrict__ wT,
                                                      float* __restrict__ part, int T) {
    __shared__ float xs[KC][TM];     // transposed: reads (kk fixed, lane varies) and
                                     // writes (k fixed per wave-instr) conflict-free

    const int tid  = threadIdx.x;
    const int lane = tid & 63;
    const int wv   = tid >> 6;                        // 0..3
    const int bx   = blockIdx.x;
    const int tile = bx >> 2;
    const int half = (bx >> 1) & 1;
    const int ks   = bx & 1;
    const int t0   = tile * TM;
    const int e0   = __builtin_amdgcn_readfirstlane(half * 80 + wv * EPW);

    // staging: thread (lane, wv) owns x[t0+lane][ cbase + wv*4 + {0..3, 16..19} ]
    const float* xrow = x + (size_t)(t0 + lane) * HIDDEN + ks * KHALF + wv * 4;

    float4 va = *(const float4*)(xrow);               // prefetch chunk 0
    float4 vb = *(const float4*)(xrow + 16);

    float acc[EPW];
#pragma unroll
    for (int j = 0; j < EPW; ++j) acc[j] = 0.f;

    const float* wbase = wT + (size_t)ks * KHALF * NEXP + e0;

    for (int c = 0; c < NCH; ++c) {
        __syncthreads();
        const int kw = wv * 4;
        xs[kw + 0][lane] = va.x;
        xs[kw + 1][lane] = va.y;
        xs[kw + 2][lane] = va.z;
        xs[kw + 3][lane] = va.w;
        xs[kw + 16][lane] = vb.x;
        xs[kw + 17][lane] = vb.y;
        xs[kw + 18][lane] = vb.z;
        xs[kw + 19][lane] = vb.w;
        __syncthreads();

        int cn = (c + 1 < NCH) ? c + 1 : c;
        va = *(const float4*)(xrow + (size_t)cn * KC);
        vb = *(const float4*)(xrow + (size_t)cn * KC + 16);

        const float* wp = wbase + (size_t)c * KC * NEXP;   // wave-uniform

        float cacc[EPW];                                   // 2-level sum (precision)
#pragma unroll
        for (int j = 0; j < EPW; ++j) cacc[j] = 0.f;

#pragma unroll
        for (int kk = 0; kk < KC; ++kk) {
            float xv = xs[kk][lane];
            const float* wr = wp + kk * NEXP;              // -> s_load
#pragma unroll
            for (int j = 0; j < EPW; ++j)
                cacc[j] = fmaf(xv, wr[j], cacc[j]);
        }
#pragma unroll
        for (int j = 0; j < EPW; ++j) acc[j] += cacc[j];
    }

    float* lp = part + (size_t)ks * T * NEXP + (size_t)(t0 + lane) * NEXP + e0;
#pragma unroll
    for (int j = 0; j < EPW; j += 4)
        *(float4*)(lp + j) = make_float4(acc[j], acc[j + 1], acc[j + 2], acc[j + 3]);
}

// ---------- K2: combine K-partials + grouped top-k, 4 threads/token ----------
#define ROWP 165   // odd stride: scan reads spread across banks

__global__ __launch_bounds__(256, 2) void moe_topk(const float* __restrict__ part,
                                                   float* __restrict__ out, int T) {
    __shared__ float rows[TM][ROWP];
    __shared__ float gmaxs[TM][NGRP];
    __shared__ float candV[TM][4][TOPK];
    __shared__ int   candI[TM][4][TOPK];

    const int tid = threadIdx.x;
    const int t0  = blockIdx.x * TM;
    const float4* p0 = (const float4*)(part + (size_t)t0 * NEXP);
    const float4* p1 = (const float4*)(part + (size_t)T * NEXP + (size_t)t0 * NEXP);

    // stage 64 rows (sum of the two K-partials), coalesced
#pragma unroll
    for (int i = 0; i < 10; ++i) {
        int f4 = tid + 256 * i;          // 2560 float4s total
        int t  = f4 / 40;
        int c4 = f4 - t * 40;
        float4 a = p0[f4];
        float4 b = p1[f4];
        float* dst = &rows[t][c4 * 4];
        dst[0] = a.x + b.x;
        dst[1] = a.y + b.y;
        dst[2] = a.z + b.z;
        dst[3] = a.w + b.w;
    }
    __syncthreads();

    const int tl  = tid >> 2;            // token within block
    const int sub = tid & 3;             // 4 threads per token; sub owns groups 2s,2s+1
    const float* row = rows[tl];

    // phase A: group maxes
#pragma unroll
    for (int gg = 0; gg < 2; ++gg) {
        int g = sub * 2 + gg;
        float m = -3e38f;
#pragma unroll
        for (int j = 0; j < GSIZE; ++j) m = fmaxf(m, row[g * GSIZE + j]);
        gmaxs[tl][g] = m;
    }
    __syncthreads();

    // top-3 groups, replicated per thread (deterministic; lowest g wins ties)
    float gm[NGRP];
#pragma unroll
    for (int g = 0; g < NGRP; ++g) gm[g] = gmaxs[tl][g];
    unsigned gmask = 0;
#pragma unroll
    for (int r = 0; r < TOPKG; ++r) {
        float bv = -3e38f; int bi = 0;
#pragma unroll
        for (int g = 0; g < NGRP; ++g) {
            bool elig = !((gmask >> g) & 1);
            if (elig && gm[g] > bv) { bv = gm[g]; bi = g; }
        }
        gmask |= 1u << bi;
    }

    // phase B: local top-6 of my (selected) groups via insertion sort.
    // ascending-e scan + strict '>' keeps lower index first on ties.
    float lv[TOPK]; int li[TOPK];
#pragma unroll
    for (int r = 0; r < TOPK; ++r) { lv[r] = -3e38f; li[r] = 9999; }
#pragma unroll
    for (int gg = 0; gg < 2; ++gg) {
        int g = sub * 2 + gg;
        if (!((gmask >> g) & 1)) continue;
#pragma unroll
        for (int j = 0; j < GSIZE; ++j) {
            int e = g * GSIZE + j;
            float v = row[e];
            if (v > lv[TOPK - 1]) {
                lv[TOPK - 1] = v; li[TOPK - 1] = e;
#pragma unroll
                for (int q = TOPK - 1; q > 0; --q) {
                    if (lv[q] > lv[q - 1]) {
                        float tv = lv[q]; lv[q] = lv[q - 1]; lv[q - 1] = tv;
                        int   ti = li[q]; li[q] = li[q - 1]; li[q - 1] = ti;
                    }
                }
            }
        }
    }
#pragma unroll
    for (int r = 0; r < TOPK; ++r) {
        candV[tl][sub][r] = lv[r];
        candI[tl][sub][r] = li[r];
    }
    __syncthreads();

    // merge 4 descending sub-lists; lists are in ascending-e order, so
    // first-max-wins across s = lowest expert index on ties (lax.top_k semantics)
    if (sub == 0) {
        int p[4] = {0, 0, 0, 0};
        float vals[TOPK]; int idxs[TOPK];
#pragma unroll
        for (int r = 0; r < TOPK; ++r) {
            float bv = -3e38f; int bs = 0;
#pragma unroll
            for (int s = 0; s < 4; ++s) {
                float hv = candV[tl][s][p[s]];
                if (hv > bv) { bv = hv; bs = s; }
            }
            vals[r] = bv;
            idxs[r] = candI[tl][bs][p[bs]];
            p[bs]++;
        }

        float m = vals[0];               // global max (its group always selected)
        float ssum = 0.f, wv6[TOPK];
#pragma unroll
        for (int r = 0; r < TOPK; ++r) { wv6[r] = expf(vals[r] - m); ssum += wv6[r]; }
        float inv = 1.f / (ssum + 1e-20f);

        int t = t0 + tl;
#pragma unroll
        for (int r = 0; r < TOPK; ++r) {
            out[(size_t)t * TOPK + r] = (float)idxs[r];
            out[(size_t)T * TOPK + (size_t)t * TOPK + r] = wv6[r] * inv;
        }
    }
}

extern "C" void kernel_launch(void* const* d_in, const int* in_sizes, int n_in,
                              void* d_out, int out_size, void* d_ws, size_t ws_size,
                              hipStream_t stream) {
    const float* x = (const float*)d_in[0];
    const float* w = (const float*)d_in[1];
    float* out = (float*)d_out;
    const int T = in_sizes[0] / HIDDEN;                  // 16384

    float* wT   = (float*)d_ws;                          // 5120*160 floats (3.1 MB)
    float* part = wT + (size_t)HIDDEN * NEXP;            // KSPLIT * T * 160 floats (20 MB)

    transpose_w<<<(HIDDEN * NEXP + 255) / 256, 256, 0, stream>>>(w, wT);
    gemm_logits<<<(T / TM) * 2 * KSPLIT, 256, 0, stream>>>(x, wT, part, T);
    moe_topk<<<T / TM, 256, 0, stream>>>(part, out, T);
}

// Round 3
// 714.218 us; speedup vs baseline: 1.4642x; 1.0292x over previous
//
#include <hip/hip_runtime.h>

#define HIDDEN 5120
#define NEXP 160
#define NGRP 8
#define GSIZE 20
#define TOPKG 3
#define TOPK 6

#define TM 64     // tokens per block (= lanes per wave)
#define KC 32     // k-chunk staged in LDS
#define EPW 20    // experts per wave; 4 waves = 80 experts = one half

// ---------- K0: transpose W [160][5120] -> wT [5120][160] ----------
// coalesced reads (idx walks w's native layout), scattered stores (fire-and-forget)
__global__ __launch_bounds__(256) void transpose_w(const float* __restrict__ w,
                                                   float* __restrict__ wT) {
    int idx = blockIdx.x * 256 + threadIdx.x;
    if (idx >= HIDDEN * NEXP) return;
    int e = idx / HIDDEN;
    int k = idx - e * HIDDEN;
    wT[(size_t)k * NEXP + e] = w[idx];
}

// ---------- K1: partial logits via scalar-broadcast FMA ----------
// lane = token (64/wave); w rows wave-uniform -> s_load into SGPRs, v_fma v,s,v.
// grid = (T/64) tiles x 2 expert-halves x KS k-splits.
// KS=4: 2048 blocks -> 8 blocks/CU -> 32 waves/CU (100% occupancy cap).
template <int KS>
__global__ __launch_bounds__(256, 8) void gemm_logits(const float* __restrict__ x,
                                                      const float* __restrict__ wT,
                                                      float* __restrict__ part, int T) {
    constexpr int KPART = HIDDEN / KS;
    constexpr int NCH   = KPART / KC;

    __shared__ float xs[KC][TM];     // transposed tile: conflict-free reads & writes

    const int tid  = threadIdx.x;
    const int lane = tid & 63;
    const int wv   = tid >> 6;                        // 0..3
    const int bx   = blockIdx.x;
    const int tile = bx / (2 * KS);                   // pow2 -> shift
    const int rem  = bx - tile * (2 * KS);
    const int half = rem / KS;
    const int ks   = rem - half * KS;
    const int t0   = tile * TM;
    const int e0   = __builtin_amdgcn_readfirstlane(half * 80 + wv * EPW);

    // staging: thread (lane, wv) owns x[t0+lane][ cbase + wv*4 + {0..3, 16..19} ]
    const float* xrow = x + (size_t)(t0 + lane) * HIDDEN + ks * KPART + wv * 4;

    float4 va = *(const float4*)(xrow);               // prefetch chunk 0
    float4 vb = *(const float4*)(xrow + 16);

    float acc[EPW];
#pragma unroll
    for (int j = 0; j < EPW; ++j) acc[j] = 0.f;

    const float* wbase = wT + (size_t)ks * KPART * NEXP + e0;

    for (int c = 0; c < NCH; ++c) {
        __syncthreads();
        const int kw = wv * 4;
        xs[kw + 0][lane] = va.x;
        xs[kw + 1][lane] = va.y;
        xs[kw + 2][lane] = va.z;
        xs[kw + 3][lane] = va.w;
        xs[kw + 16][lane] = vb.x;
        xs[kw + 17][lane] = vb.y;
        xs[kw + 18][lane] = vb.z;
        xs[kw + 19][lane] = vb.w;
        __syncthreads();

        int cn = (c + 1 < NCH) ? c + 1 : c;           // prefetch next chunk
        va = *(const float4*)(xrow + (size_t)cn * KC);
        vb = *(const float4*)(xrow + (size_t)cn * KC + 16);

        const float* wp = wbase + (size_t)c * KC * NEXP;   // wave-uniform

        float cacc[EPW];                                   // 2-level sum (precision)
#pragma unroll
        for (int j = 0; j < EPW; ++j) cacc[j] = 0.f;

#pragma unroll
        for (int kk = 0; kk < KC; ++kk) {
            float xv = xs[kk][lane];
            const float* wr = wp + kk * NEXP;              // -> s_load dwordx16+dwordx4
#pragma unroll
            for (int j = 0; j < EPW; ++j)
                cacc[j] = fmaf(xv, wr[j], cacc[j]);
        }
#pragma unroll
        for (int j = 0; j < EPW; ++j) acc[j] += cacc[j];
    }

    float* lp = part + (size_t)ks * T * NEXP + (size_t)(t0 + lane) * NEXP + e0;
#pragma unroll
    for (int j = 0; j < EPW; j += 4)
        *(float4*)(lp + j) = make_float4(acc[j], acc[j + 1], acc[j + 2], acc[j + 3]);
}

// ---------- K2: combine K-partials + grouped top-k, 4 threads/token ----------
#define ROWP 165   // odd stride spreads scan reads across banks

template <int KS>
__global__ __launch_bounds__(256, 2) void moe_topk(const float* __restrict__ part,
                                                   float* __restrict__ out, int T) {
    __shared__ float rows[TM][ROWP];
    __shared__ float gmaxs[TM][NGRP];
    __shared__ float candV[TM][4][TOPK];
    __shared__ int   candI[TM][4][TOPK];

    const int tid = threadIdx.x;
    const int t0  = blockIdx.x * TM;

    // stage 64 rows (deterministic sum of the KS partials), coalesced
#pragma unroll
    for (int i = 0; i < 10; ++i) {
        int f4 = tid + 256 * i;          // 2560 float4s = 64 tokens x 40
        int t  = f4 / 40;
        int c4 = f4 - t * 40;
        const float4* p0 = (const float4*)(part + (size_t)t0 * NEXP);
        float4 s = p0[f4];
#pragma unroll
        for (int ks = 1; ks < KS; ++ks) {
            const float4* pk = (const float4*)(part + (size_t)ks * T * NEXP + (size_t)t0 * NEXP);
            float4 a = pk[f4];
            s.x += a.x; s.y += a.y; s.z += a.z; s.w += a.w;
        }
        float* dst = &rows[t][c4 * 4];
        dst[0] = s.x; dst[1] = s.y; dst[2] = s.z; dst[3] = s.w;
    }
    __syncthreads();

    const int tl  = tid >> 2;            // token within block
    const int sub = tid & 3;             // 4 threads/token; sub owns groups 2s,2s+1
    const float* row = rows[tl];

    // phase A: group maxes
#pragma unroll
    for (int gg = 0; gg < 2; ++gg) {
        int g = sub * 2 + gg;
        float m = -3e38f;
#pragma unroll
        for (int j = 0; j < GSIZE; ++j) m = fmaxf(m, row[g * GSIZE + j]);
        gmaxs[tl][g] = m;
    }
    __syncthreads();

    // top-3 groups, replicated per thread (lowest g wins ties, matches lax.top_k)
    float gm[NGRP];
#pragma unroll
    for (int g = 0; g < NGRP; ++g) gm[g] = gmaxs[tl][g];
    unsigned gmask = 0;
#pragma unroll
    for (int r = 0; r < TOPKG; ++r) {
        float bv = -3e38f; int bi = 0;
#pragma unroll
        for (int g = 0; g < NGRP; ++g) {
            bool elig = !((gmask >> g) & 1);
            if (elig && gm[g] > bv) { bv = gm[g]; bi = g; }
        }
        gmask |= 1u << bi;
    }

    // phase B: local top-6 of my (selected) groups via stable insertion sort
    float lv[TOPK]; int li[TOPK];
#pragma unroll
    for (int r = 0; r < TOPK; ++r) { lv[r] = -3e38f; li[r] = 1 << 20; }
#pragma unroll
    for (int gg = 0; gg < 2; ++gg) {
        int g = sub * 2 + gg;
        if (!((gmask >> g) & 1)) continue;
#pragma unroll
        for (int j = 0; j < GSIZE; ++j) {
            int e = g * GSIZE + j;
            float v = row[e];
            if (v > lv[TOPK - 1]) {
                lv[TOPK - 1] = v; li[TOPK - 1] = e;
#pragma unroll
                for (int q = TOPK - 1; q > 0; --q) {
                    if (lv[q] > lv[q - 1]) {
                        float tv = lv[q]; lv[q] = lv[q - 1]; lv[q - 1] = tv;
                        int   ti = li[q]; li[q] = li[q - 1]; li[q - 1] = ti;
                    }
                }
            }
        }
    }
#pragma unroll
    for (int r = 0; r < TOPK; ++r) {
        candV[tl][sub][r] = lv[r];
        candI[tl][sub][r] = li[r];
    }
    __syncthreads();

    // merge: registers only, compile-time indices (no scratch-spilled pointers).
    // selection by lexicographic (value desc, index asc) with (pv,pi) exclusion.
    if (sub == 0) {
        float cv[4][TOPK]; int ci[4][TOPK];
#pragma unroll
        for (int s = 0; s < 4; ++s)
#pragma unroll
            for (int q = 0; q < TOPK; ++q) { cv[s][q] = candV[tl][s][q]; ci[s][q] = candI[tl][s][q]; }

        float vals[TOPK]; int idxs[TOPK];
        float pv = 3e38f; int pi = -1;
#pragma unroll
        for (int r = 0; r < TOPK; ++r) {
            float bv = -3e38f; int bi = 1 << 20;
#pragma unroll
            for (int s = 0; s < 4; ++s) {
#pragma unroll
                for (int q = 0; q < TOPK; ++q) {
                    float v = cv[s][q]; int e = ci[s][q];
                    bool elig = (v < pv) || (v == pv && e > pi);
                    bool better = (v > bv) || (v == bv && e < bi);
                    if (elig && better) { bv = v; bi = e; }
                }
            }
            vals[r] = bv; idxs[r] = bi; pv = bv; pi = bi;
        }

        float m = vals[0];               // global max (its group is always selected)
        float ssum = 0.f, wv6[TOPK];
#pragma unroll
        for (int r = 0; r < TOPK; ++r) { wv6[r] = expf(vals[r] - m); ssum += wv6[r]; }
        float inv = 1.f / (ssum + 1e-20f);

        int t = t0 + tl;
#pragma unroll
        for (int r = 0; r < TOPK; ++r) {
            out[(size_t)t * TOPK + r] = (float)idxs[r];
            out[(size_t)T * TOPK + (size_t)t * TOPK + r] = wv6[r] * inv;
        }
    }
}

extern "C" void kernel_launch(void* const* d_in, const int* in_sizes, int n_in,
                              void* d_out, int out_size, void* d_ws, size_t ws_size,
                              hipStream_t stream) {
    const float* x = (const float*)d_in[0];
    const float* w = (const float*)d_in[1];
    float* out = (float*)d_out;
    const int T = in_sizes[0] / HIDDEN;                  // 16384

    float* wT   = (float*)d_ws;                          // 5120*160 floats (3.1 MB)
    float* part = wT + (size_t)HIDDEN * NEXP;

    transpose_w<<<(HIDDEN * NEXP + 255) / 256, 256, 0, stream>>>(w, wT);

    size_t need4 = ((size_t)HIDDEN * NEXP + (size_t)4 * T * NEXP) * sizeof(float);
    if (ws_size >= need4) {
        gemm_logits<4><<<(T / TM) * 2 * 4, 256, 0, stream>>>(x, wT, part, T);
        moe_topk<4><<<T / TM, 256, 0, stream>>>(part, out, T);
    } else {
        gemm_logits<2><<<(T / TM) * 2 * 2, 256, 0, stream>>>(x, wT, part, T);
        moe_topk<2><<<T / TM, 256, 0, stream>>>(part, out, T);
    }
}